// Round 4
// baseline (854.530 us; speedup 1.0000x reference)
//
#include <hip/hip_runtime.h>
#include <math.h>

typedef _Float16 f16;
typedef _Float16 half8 __attribute__((ext_vector_type(8)));
typedef float float4v __attribute__((ext_vector_type(4)));

#define MFMA16(a, b, c) __builtin_amdgcn_mfma_f32_16x16x32_f16((a), (b), (c), 0, 0, 0)

// problem: B=4096 L=32 V=50000 D=300 H=6 HD=50 ; K padded to 320
// ---------------- ws layout (bytes) ----------------
#define WQKV_OFF 0u          // f16 [1024][320]  (rows 0-299 Wq*rs, 320-619 Wk, 640-939 Wv, rest 0)
#define BQKV_OFF 655360u     // f32 [1024]
#define WO_OFF   659456u     // f16 [320][320]   Wo[n][k], pads 0
#define WOT_OFF  864256u     // f16 [320][320]   Wo^T
#define WVA_OFF  1069056u    // f16 [320][320]   (Va@Wo)[n][k], pads 0
#define BVA_OFF  1273856u    // f32 [320]        Va@bo+ba, pads 0
#define AG_OFF   1275392u    // f32 [131072]
#define CBAR_OFF 1799680u    // f16 [4096][320]
#define XC_OFF   4421120u    // f16 [131072][320]  x, later overwritten in-place by ctx

// ---------------- repack1 ----------------
__global__ void repack1(const float* __restrict__ Wq, const float* __restrict__ Wk,
                        const float* __restrict__ Wv, const float* __restrict__ Wo,
                        const float* __restrict__ bq, const float* __restrict__ bk,
                        const float* __restrict__ bv,
                        f16* __restrict__ wqkv, f16* __restrict__ wo16,
                        f16* __restrict__ wot, float* __restrict__ bqkv) {
    int idx = blockIdx.x * 256 + threadIdx.x;
    const float rs = 0.14142135623730951f;  // 1/sqrt(50)
    if (idx < 327680) {  // Wqkv [1024][320]
        int row = idx / 320, col = idx % 320;
        int g = row / 320, r = row % 320;
        float v = 0.f;
        if (r < 300 && col < 300) {
            if (g == 0) v = Wq[r * 300 + col] * rs;
            else if (g == 1) v = Wk[r * 300 + col];
            else if (g == 2) v = Wv[r * 300 + col];
        }
        wqkv[idx] = (f16)v;
    } else if (idx < 430080) {  // Wo_f16 [320][320]
        int j = idx - 327680;
        int n = j / 320, k = j % 320;
        wo16[j] = (f16)((n < 300 && k < 300) ? Wo[n * 300 + k] : 0.f);
    } else if (idx < 532480) {  // WoT [320][320]
        int j = idx - 430080;
        int n = j / 320, k = j % 320;
        wot[j] = (f16)((n < 300 && k < 300) ? Wo[k * 300 + n] : 0.f);
    } else if (idx < 533504) {  // bqkv [1024]
        int n = idx - 532480;
        int g = n / 320, r = n % 320;
        float v = 0.f;
        if (r < 300) {
            if (g == 0) v = bq[r] * rs;
            else if (g == 1) v = bk[r];
            else if (g == 2) v = bv[r];
        }
        bqkv[n] = v;
    }
}

// ---------------- repack2: Wva = Va @ Wo ----------------
__global__ void repack2(const float* __restrict__ Va, const f16* __restrict__ wot,
                        f16* __restrict__ wva) {
    int bt = blockIdx.x;  // 400 = 20*20
    int mt = bt / 20, nt = bt % 20;
    int lane = threadIdx.x & 63;
    int lr = lane & 15, quad = lane >> 4;
    float4v acc = {0.f, 0.f, 0.f, 0.f};
    int m = mt * 16 + lr;
    for (int ks = 0; ks < 10; ++ks) {
        int c = ks * 32 + quad * 8;
        half8 af;
#pragma unroll
        for (int j = 0; j < 8; ++j)
            af[j] = (f16)((m < 300 && (c + j) < 300) ? Va[m * 300 + c + j] : 0.f);
        half8 bf = *(const half8*)&wot[(nt * 16 + lr) * 320 + c];
        acc = MFMA16(af, bf, acc);
    }
#pragma unroll
    for (int r = 0; r < 4; ++r)
        wva[(mt * 16 + quad * 4 + r) * 320 + nt * 16 + lr] = (f16)acc[r];
}

// ---------------- repack3: bva = Va @ bo + ba ----------------
__global__ void repack3(const float* __restrict__ Va, const float* __restrict__ bo,
                        const float* __restrict__ ba, float* __restrict__ bva) {
    int j = threadIdx.x;  // 320
    float s = 0.f;
    if (j < 300) {
        for (int k = 0; k < 300; ++k) s += Va[j * 300 + k] * bo[k];
        s += ba[j];
    }
    bva[j] = s;
}

// ---------------- gather: x = emb[title] + pos, f16 [131072][320] ----------
__global__ void gather_kernel(const int* __restrict__ title, const float* __restrict__ emb,
                              const float* __restrict__ pos, f16* __restrict__ x) {
    int s = blockIdx.x * 256 + threadIdx.x;
    int row = s / 40, cs = (s % 40) * 8;
    int t = title[row];
    int l = row & 31;
    half8 h;
    if (cs + 8 <= 300) {
        float4v e0 = *(const float4v*)&emb[t * 300 + cs];
        float4v e1 = *(const float4v*)&emb[t * 300 + cs + 4];
        float4v p0 = *(const float4v*)&pos[l * 300 + cs];
        float4v p1 = *(const float4v*)&pos[l * 300 + cs + 4];
#pragma unroll
        for (int j = 0; j < 4; ++j) { h[j] = (f16)(e0[j] + p0[j]); h[4 + j] = (f16)(e1[j] + p1[j]); }
    } else {
#pragma unroll
        for (int j = 0; j < 8; ++j) {
            int c = cs + j;
            h[j] = (f16)((c < 300) ? emb[t * 300 + c] + pos[l * 300 + c] : 0.f);
        }
    }
    *(half8*)&x[row * 320 + cs] = h;
}

// ---------------- fused QKV GEMM + attention, one block per item ----------
// LDS: xA 21KB + B dbuf 43KB + qL/kL 55KB + vT 24.5KB = 143,872 B -> 1 block/CU
__global__ __launch_bounds__(512, 2) void qkvattn_kernel(
    const f16* __restrict__ wqkv, const float* __restrict__ bqkv, f16* __restrict__ xc) {
    __shared__ __align__(16) f16 xA[32 * 328];
    __shared__ __align__(16) f16 Bt[2][64 * 168];
    __shared__ __align__(16) f16 qL[6 * 32 * 72];
    __shared__ __align__(16) f16 kL[6 * 32 * 72];
    __shared__ __align__(16) f16 vT[6 * 64 * 32];
    const int ib = blockIdx.x, tid = threadIdx.x;
    const int w = tid >> 6, lane = tid & 63, lr = lane & 15, quad = lane >> 4;
    const int nsub = w & 3, mh = w >> 2;
    const float4v vz = {0.f, 0.f, 0.f, 0.f};

    // zero attention staging (pads must be 0)
    {
        int* z0 = (int*)qL;
        int* z1 = (int*)kL;
        int* z2 = (int*)vT;
        for (int i = tid; i < 6912; i += 512) { z0[i] = 0; z1[i] = 0; }
        for (int i = tid; i < 6144; i += 512) z2[i] = 0;
    }
    // stage x rows (padded stride 328; cols 300-319 already zero in xc)
    for (int i = tid; i < 1280; i += 512) {
        int row = i / 40, g = i - row * 40;
        *(half8*)&xA[row * 328 + g * 8] = *(const half8*)&xc[(ib * 32 + row) * 320 + g * 8];
    }
    // preload first B chunk (t=0, kc=0)
    for (int i = tid; i < 1280; i += 512) {
        int row = i / 20, g = i - row * 20;
        *(half8*)&Bt[0][row * 168 + g * 8] = *(const half8*)&wqkv[row * 320 + g * 8];
    }
    __syncthreads();

    // --- QKV GEMM: n-loop 16 tiles of 64, k 2 chunks of 160, B double-buffered ---
    int cur = 0;
    for (int t = 0; t < 16; ++t) {
        float4v acc = vz;
        for (int kc = 0; kc < 2; ++kc) {
            int nx = t * 2 + kc + 1;
            if (nx < 32) {  // prefetch next chunk into other buffer
                const f16* src = wqkv + (nx >> 1) * 64 * 320 + (nx & 1) * 160;
                f16* dst = Bt[cur ^ 1];
                for (int i = tid; i < 1280; i += 512) {
                    int row = i / 20, g = i - row * 20;
                    *(half8*)&dst[row * 168 + g * 8] = *(const half8*)&src[row * 320 + g * 8];
                }
            }
            const f16* Ap = xA + (mh * 16 + lr) * 328 + kc * 160 + quad * 8;
            const f16* Bp = Bt[cur] + (nsub * 16 + lr) * 168 + quad * 8;
#pragma unroll
            for (int ks = 0; ks < 5; ++ks) {
                half8 a = *(const half8*)&Ap[ks * 32];
                half8 b = *(const half8*)&Bp[ks * 32];
                acc = MFMA16(a, b, acc);
            }
            cur ^= 1;
            __syncthreads();
        }
        // epilogue: scatter this 32x64 result slab into q/k/v LDS
        int n = t * 64 + nsub * 16 + lr;
        int wi = n / 320;
        int cc = n - wi * 320;
        if (wi < 3 && cc < 300) {
            int h = cc / 50, d = cc - h * 50;
            float bb = bqkv[n];
#pragma unroll
            for (int r = 0; r < 4; ++r) {
                int row = mh * 16 + quad * 4 + r;
                float v = acc[r] + bb;
                if (wi == 0) qL[(h * 32 + row) * 72 + d] = (f16)v;
                else if (wi == 1) kL[(h * 32 + row) * 72 + d] = (f16)v;
                else vT[(h * 64 + d) * 32 + row] = (f16)v;
            }
        }
    }
    __syncthreads();

    // --- attention: wave h owns head h (waves 6,7 idle) ---
    const int h = w;
    float4v s00 = vz, s01 = vz, s10 = vz, s11 = vz;
    if (w < 6) {
#pragma unroll
        for (int ks = 0; ks < 2; ++ks) {
            int c = ks * 32 + quad * 8;
            half8 aq0 = *(const half8*)&qL[(h * 32 + lr) * 72 + c];
            half8 aq1 = *(const half8*)&qL[(h * 32 + 16 + lr) * 72 + c];
            half8 bk0 = *(const half8*)&kL[(h * 32 + lr) * 72 + c];
            half8 bk1 = *(const half8*)&kL[(h * 32 + 16 + lr) * 72 + c];
            s00 = MFMA16(aq0, bk0, s00);
            s01 = MFMA16(aq0, bk1, s01);
            s10 = MFMA16(aq1, bk0, s10);
            s11 = MFMA16(aq1, bk1, s11);
        }
        f16* ph = qL + h * 32 * 72;  // P aliases this head's q region (dead)
#pragma unroll
        for (int mt = 0; mt < 2; ++mt) {
            float4v sv0 = mt ? s10 : s00;
            float4v sv1 = mt ? s11 : s01;
#pragma unroll
            for (int r = 0; r < 4; ++r) {
                float v0 = sv0[r], v1 = sv1[r];
                float m = fmaxf(v0, v1);
#pragma unroll
                for (int off = 1; off < 16; off <<= 1) m = fmaxf(m, __shfl_xor(m, off, 64));
                float e0 = expf(v0 - m), e1 = expf(v1 - m);
                float ss = e0 + e1;
#pragma unroll
                for (int off = 1; off < 16; off <<= 1) ss += __shfl_xor(ss, off, 64);
                float inv = 1.0f / ss;
                int row = mt * 16 + quad * 4 + r;
                ph[row * 40 + lr] = (f16)(e0 * inv);
                ph[row * 40 + 16 + lr] = (f16)(e1 * inv);
            }
        }
    }
    __syncthreads();
    if (w < 6) {
        f16* ph = qL + h * 32 * 72;
        half8 aw0 = *(const half8*)&ph[lr * 40 + quad * 8];
        half8 aw1 = *(const half8*)&ph[(16 + lr) * 40 + quad * 8];
        float4v c0[4], c1[4];
#pragma unroll
        for (int nt = 0; nt < 4; ++nt) { c0[nt] = vz; c1[nt] = vz; }
#pragma unroll
        for (int nt = 0; nt < 4; ++nt) {
            half8 bvf = *(const half8*)&vT[(h * 64 + nt * 16 + lr) * 32 + quad * 8];
            c0[nt] = MFMA16(aw0, bvf, c0[nt]);
            c1[nt] = MFMA16(aw1, bvf, c1[nt]);
        }
        // ctx into xA (cols 300-319 keep their zeros)
#pragma unroll
        for (int mt = 0; mt < 2; ++mt)
#pragma unroll
            for (int nt = 0; nt < 4; ++nt)
#pragma unroll
                for (int r = 0; r < 4; ++r) {
                    int d = nt * 16 + lr;
                    if (d < 50) {
                        int row = mt * 16 + quad * 4 + r;
                        float4v cc = mt ? c1[nt] : c0[nt];
                        xA[row * 328 + h * 50 + d] = (f16)cc[r];
                    }
                }
    }
    __syncthreads();
    // coalesced ctx store (overwrites x in place)
    for (int i = tid; i < 1280; i += 512) {
        int row = i / 40, g = i - row * 40;
        *(half8*)&xc[(ib * 32 + row) * 320 + g * 8] = *(const half8*)&xA[row * 328 + g * 8];
    }
}

// ---------------- va: a = (tanh(ctx@Wva^T + bva))@qw, M=64/block -----------
// LDS 63,744 B -> 2 blocks/CU
__global__ __launch_bounds__(512, 2) void va_kernel(
    const f16* __restrict__ ctx, const f16* __restrict__ wva,
    const float* __restrict__ bva, const float* __restrict__ qw, float* __restrict__ ag) {
    __shared__ __align__(16) f16 cA[64 * 328];
    __shared__ __align__(16) f16 Bs[64 * 168];
    __shared__ float aL[64];
    const int mb = blockIdx.x, tid = threadIdx.x;
    const int w = tid >> 6, lane = tid & 63, lr = lane & 15, quad = lane >> 4;
    const int nsub = w & 3, mh = w >> 2;
    const float4v vz = {0.f, 0.f, 0.f, 0.f};
    if (tid < 64) aL[tid] = 0.f;
    for (int i = tid; i < 2560; i += 512) {
        int row = i / 40, g = i - row * 40;
        *(half8*)&cA[row * 328 + g * 8] = *(const half8*)&ctx[(mb * 64 + row) * 320 + g * 8];
    }
    float ps0[4] = {0.f, 0.f, 0.f, 0.f};
    float ps1[4] = {0.f, 0.f, 0.f, 0.f};
    for (int t = 0; t < 5; ++t) {
        float4v acc0 = vz, acc1 = vz;
        for (int kc = 0; kc < 2; ++kc) {
            __syncthreads();  // prior compute done (first: cA/aL visible)
            const f16* src = wva + t * 64 * 320 + kc * 160;
            for (int i = tid; i < 1280; i += 512) {
                int row = i / 20, g = i - row * 20;
                *(half8*)&Bs[row * 168 + g * 8] = *(const half8*)&src[row * 320 + g * 8];
            }
            __syncthreads();
            const f16* Bp = Bs + (nsub * 16 + lr) * 168 + quad * 8;
            const f16* A0 = cA + (mh * 32 + lr) * 328 + kc * 160 + quad * 8;
            const f16* A1 = A0 + 16 * 328;
#pragma unroll
            for (int ks = 0; ks < 5; ++ks) {
                half8 b = *(const half8*)&Bp[ks * 32];
                half8 a0 = *(const half8*)&A0[ks * 32];
                half8 a1 = *(const half8*)&A1[ks * 32];
                acc0 = MFMA16(a0, b, acc0);
                acc1 = MFMA16(a1, b, acc1);
            }
        }
        int n = t * 64 + nsub * 16 + lr;
        float bb = bva[n];
        float qq = (n < 300) ? qw[n] : 0.f;
#pragma unroll
        for (int r = 0; r < 4; ++r) {
            ps0[r] += tanhf(acc0[r] + bb) * qq;
            ps1[r] += tanhf(acc1[r] + bb) * qq;
        }
    }
#pragma unroll
    for (int r = 0; r < 4; ++r) {
#pragma unroll
        for (int off = 1; off < 16; off <<= 1) {
            ps0[r] += __shfl_xor(ps0[r], off, 64);
            ps1[r] += __shfl_xor(ps1[r], off, 64);
        }
    }
    if (lr == 0) {
#pragma unroll
        for (int r = 0; r < 4; ++r) {
            atomicAdd(&aL[mh * 32 + quad * 4 + r], ps0[r]);
            atomicAdd(&aL[mh * 32 + 16 + quad * 4 + r], ps1[r]);
        }
    }
    __syncthreads();
    if (tid < 64) ag[mb * 64 + tid] = aL[tid];
}

// ---------------- pool: alpha = softmax(a), cbar = alpha @ ctx -------------
__global__ void pool_kernel(const float* __restrict__ ag, const f16* __restrict__ ctx,
                            f16* __restrict__ cbar) {
    __shared__ float alpha[32];
    int ib = blockIdx.x, tid = threadIdx.x;
    if (tid < 32) {
        float av = ag[ib * 32 + tid];
        float m = av;
#pragma unroll
        for (int off = 1; off < 32; off <<= 1) m = fmaxf(m, __shfl_xor(m, off, 32));
        float e = expf(av - m);
        float ssum = e;
#pragma unroll
        for (int off = 1; off < 32; off <<= 1) ssum += __shfl_xor(ssum, off, 32);
        alpha[tid] = e / ssum;
    }
    __syncthreads();
    for (int c = tid; c < 320; c += 128) {
        float acc = 0.f;
#pragma unroll
        for (int l = 0; l < 32; ++l) acc += alpha[l] * (float)ctx[(ib * 32 + l) * 320 + c];
        cbar[ib * 320 + c] = (f16)acc;
    }
}

// ---------------- out = cbar @ Wo^T + bo, f32 [4096][300] ------------------
__global__ __launch_bounds__(512) void out_kernel(
    const f16* __restrict__ cbar, const f16* __restrict__ wo16,
    const float* __restrict__ bo, float* __restrict__ out) {
    int mb = blockIdx.x, tid = threadIdx.x;  // M=32 per block, 128 blocks
    int w = tid >> 6, lane = tid & 63, lr = lane & 15, quad = lane >> 4;
    int mt = w >> 2, q4 = w & 3;
    const float4v vz = {0.f, 0.f, 0.f, 0.f};
    float4v acc[5];
#pragma unroll
    for (int j = 0; j < 5; ++j) acc[j] = vz;
    int arow = (mb * 32 + mt * 16 + lr) * 320;
    for (int ks = 0; ks < 10; ++ks) {
        int c = ks * 32 + quad * 8;
        half8 af = *(const half8*)&cbar[arow + c];
#pragma unroll
        for (int j = 0; j < 5; ++j) {
            half8 bf = *(const half8*)&wo16[((q4 * 5 + j) * 16 + lr) * 320 + c];
            acc[j] = MFMA16(af, bf, acc[j]);
        }
    }
#pragma unroll
    for (int j = 0; j < 5; ++j) {
        int n = (q4 * 5 + j) * 16 + lr;
        if (n < 300) {
            float bb = bo[n];
#pragma unroll
            for (int r = 0; r < 4; ++r) {
                int row = mb * 32 + mt * 16 + quad * 4 + r;
                out[row * 300 + n] = acc[j][r] + bb;
            }
        }
    }
}

// ---------------- host launcher ----------------
extern "C" void kernel_launch(void* const* d_in, const int* in_sizes, int n_in,
                              void* d_out, int out_size, void* d_ws, size_t ws_size,
                              hipStream_t stream) {
    const int* title = (const int*)d_in[0];
    const float* emb = (const float*)d_in[1];
    const float* pos = (const float*)d_in[2];
    const float* Wq = (const float*)d_in[3];
    const float* bq = (const float*)d_in[4];
    const float* Wk = (const float*)d_in[5];
    const float* bk = (const float*)d_in[6];
    const float* Wv = (const float*)d_in[7];
    const float* bv = (const float*)d_in[8];
    const float* Wo = (const float*)d_in[9];
    const float* bo = (const float*)d_in[10];
    const float* Va = (const float*)d_in[11];
    const float* ba = (const float*)d_in[12];
    const float* qw = (const float*)d_in[13];
    char* ws = (char*)d_ws;
    float* out = (float*)d_out;

    f16* wqkv = (f16*)(ws + WQKV_OFF);
    float* bqkv = (float*)(ws + BQKV_OFF);
    f16* wo16 = (f16*)(ws + WO_OFF);
    f16* wot = (f16*)(ws + WOT_OFF);
    f16* wva = (f16*)(ws + WVA_OFF);
    float* bva = (float*)(ws + BVA_OFF);
    float* ag = (float*)(ws + AG_OFF);
    f16* cbar = (f16*)(ws + CBAR_OFF);
    f16* xc = (f16*)(ws + XC_OFF);

    repack1<<<2084, 256, 0, stream>>>(Wq, Wk, Wv, Wo, bq, bk, bv, wqkv, wo16, wot, bqkv);
    repack2<<<400, 64, 0, stream>>>(Va, wot, wva);
    repack3<<<1, 320, 0, stream>>>(Va, bo, ba, bva);
    gather_kernel<<<20480, 256, 0, stream>>>(title, emb, pos, xc);
    qkvattn_kernel<<<4096, 512, 0, stream>>>(wqkv, bqkv, xc);
    va_kernel<<<2048, 512, 0, stream>>>(xc, wva, bva, qw, ag);
    pool_kernel<<<4096, 128, 0, stream>>>(ag, xc, cbar);
    out_kernel<<<128, 512, 0, stream>>>(cbar, wo16, bo, out);
}

// Round 5
// 501.384 us; speedup vs baseline: 1.7043x; 1.7043x over previous
//
#include <hip/hip_runtime.h>
#include <math.h>

typedef _Float16 f16;
typedef _Float16 half8 __attribute__((ext_vector_type(8)));
typedef float float4v __attribute__((ext_vector_type(4)));

#define MFMA16(a, b, c) __builtin_amdgcn_mfma_f32_16x16x32_f16((a), (b), (c), 0, 0, 0)

// problem: B=4096 L=32 V=50000 D=300 H=6 HD=50 ; K padded to 320
// Fragment-swizzled layout: element (n, k) of a [Nt*16][320] matrix lives at
//   F[((n>>4)*10 + (k>>5))*512 + (((k>>3)&3)*16 + (n&15))*8 + (k&7)]
// so a wave's MFMA B-frag (n=nt*16+lr, k=ks*32+quad*8+j) is one contiguous
// 16B/lane load. Same layout for A (m rows).

// ---------------- ws layout (bytes) ----------------
#define WQKV_OFF 0u          // f16 frag-swizzled [64 ntiles] (q*rs | k | v rows, pads 0)
#define BQKV_OFF 655360u     // f32 [1024]
#define WO_OFF   659456u     // f16 frag-swizzled [20 ntiles] Wo
#define WVA_OFF  864256u     // f16 frag-swizzled [20 ntiles] Va@Wo
#define BVA_OFF  1069056u    // f32 [320]  Va@bo+ba (pads 0)
#define CBAR_OFF 1070336u    // f16 [4096][320] row-major
#define XF_OFF   3691776u    // f16 frag-swizzled x / ctx: per item 20 fragblks of 512

// ---------------- repack1: Wqkv + Wo -> frag-swizzled f16, bqkv ----------
__global__ void repack1(const float* __restrict__ Wq, const float* __restrict__ Wk,
                        const float* __restrict__ Wv, const float* __restrict__ Wo,
                        const float* __restrict__ bq, const float* __restrict__ bk,
                        const float* __restrict__ bv,
                        f16* __restrict__ wqkvF, f16* __restrict__ wo16F,
                        float* __restrict__ bqkv) {
    int idx = blockIdx.x * 256 + threadIdx.x;
    const float rs = 0.14142135623730951f;  // 1/sqrt(50)
    if (idx < 327680) {  // wqkvF: 64 ntiles
        int ntile = idx / 5120, rem = idx - ntile * 5120;
        int ks = rem / 512, r2 = rem - ks * 512;
        int lane = r2 >> 3, j = r2 & 7;
        int n = ntile * 16 + (lane & 15);
        int k = ks * 32 + (lane >> 4) * 8 + j;
        int g = n / 320, r = n - g * 320;
        float v = 0.f;
        if (r < 300 && k < 300) {
            if (g == 0) v = Wq[r * 300 + k] * rs;
            else if (g == 1) v = Wk[r * 300 + k];
            else if (g == 2) v = Wv[r * 300 + k];
        }
        wqkvF[idx] = (f16)v;
    } else if (idx < 430080) {  // wo16F: 20 ntiles
        int t = idx - 327680;
        int ntile = t / 5120, rem = t - ntile * 5120;
        int ks = rem / 512, r2 = rem - ks * 512;
        int lane = r2 >> 3, j = r2 & 7;
        int n = ntile * 16 + (lane & 15);
        int k = ks * 32 + (lane >> 4) * 8 + j;
        wo16F[t] = (f16)((n < 300 && k < 300) ? Wo[n * 300 + k] : 0.f);
    } else if (idx < 431104) {  // bqkv [1024]
        int n = idx - 430080;
        int g = n / 320, r = n - g * 320;
        float v = 0.f;
        if (r < 300) {
            if (g == 0) v = bq[r] * rs;
            else if (g == 1) v = bk[r];
            else if (g == 2) v = bv[r];
        }
        bqkv[n] = v;
    }
}

// ---------------- repack2: Wva = Va @ Wo -> frag-swizzled ----------------
__global__ void repack2(const float* __restrict__ Va, const float* __restrict__ Wo,
                        f16* __restrict__ wvaF) {
    int bt = blockIdx.x;  // 400 = 20*20
    int mt = bt / 20, nt = bt % 20;
    int lane = threadIdx.x & 63;
    int lr = lane & 15, quad = lane >> 4;
    float4v acc = {0.f, 0.f, 0.f, 0.f};
    int m = mt * 16 + lr;   // Wva row
    int nn = nt * 16 + lr;  // Wva col (= Wo output dim)
    for (int ks = 0; ks < 10; ++ks) {
        int c = ks * 32 + quad * 8;
        half8 af, bf;
#pragma unroll
        for (int j = 0; j < 8; ++j) {
            int cc = c + j;
            af[j] = (f16)((m < 300 && cc < 300) ? Va[m * 300 + cc] : 0.f);
            bf[j] = (f16)((nn < 300 && cc < 300) ? Wo[cc * 300 + nn] : 0.f);
        }
        acc = MFMA16(af, bf, acc);
    }
#pragma unroll
    for (int r = 0; r < 4; ++r) {
        int row = mt * 16 + quad * 4 + r;  // Wva row index
        int col = nt * 16 + lr;            // Wva col index (k of va GEMM)
        int addr = ((row >> 4) * 10 + (col >> 5)) * 512 +
                   (((col >> 3) & 3) * 16 + (row & 15)) * 8 + (col & 7);
        wvaF[addr] = (f16)acc[r];
    }
}

// ---------------- repack3: bva = Va @ bo + ba ----------------
__global__ void repack3(const float* __restrict__ Va, const float* __restrict__ bo,
                        const float* __restrict__ ba, float* __restrict__ bva) {
    int j = threadIdx.x;  // 320
    float s = 0.f;
    if (j < 300) {
        for (int k = 0; k < 300; ++k) s += Va[j * 300 + k] * bo[k];
        s += ba[j];
    }
    bva[j] = s;
}

// ---------------- gather: x = emb[title] + pos, frag-swizzled ------------
__global__ void gather_kernel(const int* __restrict__ title, const float* __restrict__ emb,
                              const float* __restrict__ pos, f16* __restrict__ xF) {
    int c = blockIdx.x * 256 + threadIdx.x;  // < 131072*40
    int fragblk = c >> 6, lane = c & 63;
    int item = fragblk / 20, rem = fragblk - item * 20;
    int mt = rem / 10, ks = rem - mt * 10;
    int lr = lane & 15, quad = lane >> 4;
    int row = item * 32 + mt * 16 + lr;
    int col = ks * 32 + quad * 8;
    int t = title[row];
    int l = row & 31;
    half8 h;
    if (col + 8 <= 300) {
        float4v e0 = *(const float4v*)&emb[t * 300 + col];
        float4v e1 = *(const float4v*)&emb[t * 300 + col + 4];
        float4v p0 = *(const float4v*)&pos[l * 300 + col];
        float4v p1 = *(const float4v*)&pos[l * 300 + col + 4];
#pragma unroll
        for (int j = 0; j < 4; ++j) { h[j] = (f16)(e0[j] + p0[j]); h[4 + j] = (f16)(e1[j] + p1[j]); }
    } else {
#pragma unroll
        for (int j = 0; j < 8; ++j) {
            int cc = col + j;
            h[j] = (f16)((cc < 300) ? emb[t * 300 + cc] + pos[l * 300 + cc] : 0.f);
        }
    }
    *(half8*)&xF[c * 8] = h;
}

// ---------------- fused QKV GEMM + attention: 2 items/block, 1024 thr ----
// LDS: qL/kL [12*32][72], vT [12*64][32] = 159,744 B -> 1 block/CU, 16 waves
__global__ __launch_bounds__(1024, 4) void qkvattn_kernel(
    const f16* __restrict__ xF, const f16* __restrict__ wqkvF,
    const float* __restrict__ bqkv, f16* __restrict__ xFo) {
    __shared__ __align__(16) f16 qL[12 * 32 * 72];
    __shared__ __align__(16) f16 kL[12 * 32 * 72];
    __shared__ __align__(16) f16 vT[12 * 64 * 32];
    const int ib = blockIdx.x, tid = threadIdx.x;
    const int w = tid >> 6, lane = tid & 63, lr = lane & 15, quad = lane >> 4;
    const float4v vz = {0.f, 0.f, 0.f, 0.f};

    // zero q/k/v staging (pads must be 0)
    for (int i = tid; i < 13824; i += 1024) { ((int*)qL)[i] = 0; ((int*)kL)[i] = 0; }
    for (int i = tid; i < 12288; i += 1024) ((int*)vT)[i] = 0;
    __syncthreads();

    // --- GEMM: M=64 (items ib*2, ib*2+1), N=1024, K=320; wave owns 4 ntiles ---
    float4v acc[4][4];
#pragma unroll
    for (int mt = 0; mt < 4; ++mt)
#pragma unroll
        for (int j = 0; j < 4; ++j) acc[mt][j] = vz;
    for (int ks = 0; ks < 10; ++ks) {
        half8 a[4];
#pragma unroll
        for (int mt = 0; mt < 4; ++mt)
            a[mt] = *(const half8*)&xF[(((ib * 4 + mt) * 10 + ks) * 64 + lane) * 8];
#pragma unroll
        for (int j = 0; j < 4; ++j) {
            half8 bf = *(const half8*)&wqkvF[((((w * 4 + j) * 10) + ks) * 64 + lane) * 8];
#pragma unroll
            for (int mt = 0; mt < 4; ++mt) acc[mt][j] = MFMA16(a[mt], bf, acc[mt][j]);
        }
    }
    // epilogue: scatter q/k/v into LDS
#pragma unroll
    for (int j = 0; j < 4; ++j) {
        int n = (w * 4 + j) * 16 + lr;
        int wi = n / 320, cc = n - wi * 320;
        if (wi < 3 && cc < 300) {
            int h = cc / 50, d = cc - h * 50;
            float bb = bqkv[n];
#pragma unroll
            for (int mt = 0; mt < 4; ++mt) {
                int hh = (mt >> 1) * 6 + h;
#pragma unroll
                for (int r = 0; r < 4; ++r) {
                    int row = (mt & 1) * 16 + quad * 4 + r;
                    float v = acc[mt][j][r] + bb;
                    if (wi == 0) qL[(hh * 32 + row) * 72 + d] = (f16)v;
                    else if (wi == 1) kL[(hh * 32 + row) * 72 + d] = (f16)v;
                    else vT[(hh * 64 + d) * 32 + row] = (f16)v;
                }
            }
        }
    }
    __syncthreads();

    // --- attention phase 1: wave hh (<12) computes scores + softmax -> P ---
    const int hh = w;
    if (w < 12) {
        float4v s00 = vz, s01 = vz, s10 = vz, s11 = vz;
#pragma unroll
        for (int ks = 0; ks < 2; ++ks) {
            int c = ks * 32 + quad * 8;
            half8 aq0 = *(const half8*)&qL[(hh * 32 + lr) * 72 + c];
            half8 aq1 = *(const half8*)&qL[(hh * 32 + 16 + lr) * 72 + c];
            half8 bk0 = *(const half8*)&kL[(hh * 32 + lr) * 72 + c];
            half8 bk1 = *(const half8*)&kL[(hh * 32 + 16 + lr) * 72 + c];
            s00 = MFMA16(aq0, bk0, s00);
            s01 = MFMA16(aq0, bk1, s01);
            s10 = MFMA16(aq1, bk0, s10);
            s11 = MFMA16(aq1, bk1, s11);
        }
        f16* ph = qL + hh * 32 * 72;  // P aliases this head's q region (dead)
#pragma unroll
        for (int mt = 0; mt < 2; ++mt) {
            float4v sv0 = mt ? s10 : s00;
            float4v sv1 = mt ? s11 : s01;
#pragma unroll
            for (int r = 0; r < 4; ++r) {
                float v0 = sv0[r], v1 = sv1[r];
                float m = fmaxf(v0, v1);
#pragma unroll
                for (int off = 1; off < 16; off <<= 1) m = fmaxf(m, __shfl_xor(m, off, 64));
                float e0 = expf(v0 - m), e1 = expf(v1 - m);
                float ss = e0 + e1;
#pragma unroll
                for (int off = 1; off < 16; off <<= 1) ss += __shfl_xor(ss, off, 64);
                float inv = 1.0f / ss;
                int row = mt * 16 + quad * 4 + r;
                ph[row * 40 + lr] = (f16)(e0 * inv);
                ph[row * 40 + 16 + lr] = (f16)(e1 * inv);
            }
        }
    }
    __syncthreads();

    // --- attention phase 2: ctx = P @ V -> row-major scratch (reuses kL) ---
    f16* scratch = kL;  // [64 rows][328]
    for (int i = tid; i < 64 * 20; i += 1024) {  // zero pad cols 300..319
        int row = i / 20, cc = 300 + (i - row * 20);
        scratch[row * 328 + cc] = (f16)0.f;
    }
    if (w < 12) {
        int il = hh / 6, h = hh - il * 6;
        f16* ph = qL + hh * 32 * 72;
        half8 aw0 = *(const half8*)&ph[lr * 40 + quad * 8];
        half8 aw1 = *(const half8*)&ph[(16 + lr) * 40 + quad * 8];
        float4v c0[4], c1[4];
#pragma unroll
        for (int nt = 0; nt < 4; ++nt) { c0[nt] = vz; c1[nt] = vz; }
#pragma unroll
        for (int nt = 0; nt < 4; ++nt) {
            half8 bvf = *(const half8*)&vT[(hh * 64 + nt * 16 + lr) * 32 + quad * 8];
            c0[nt] = MFMA16(aw0, bvf, c0[nt]);
            c1[nt] = MFMA16(aw1, bvf, c1[nt]);
        }
#pragma unroll
        for (int mt = 0; mt < 2; ++mt)
#pragma unroll
            for (int nt = 0; nt < 4; ++nt)
#pragma unroll
                for (int r = 0; r < 4; ++r) {
                    int d = nt * 16 + lr;
                    if (d < 50) {
                        int row = il * 32 + mt * 16 + quad * 4 + r;
                        float4v cv = mt ? c1[nt] : c0[nt];
                        scratch[row * 328 + h * 50 + d] = (f16)cv[r];
                    }
                }
    }
    __syncthreads();
    // coalesced ctx write-out in frag layout (overwrites x)
    for (int c = tid; c < 2560; c += 1024) {
        int fragblk = c >> 6, lane2 = c & 63;
        int il = fragblk / 20, rem = fragblk - il * 20;
        int mtl = rem / 10, ks = rem - mtl * 10;
        int row = il * 32 + mtl * 16 + (lane2 & 15);
        int col = ks * 32 + (lane2 >> 4) * 8;
        *(half8*)&xFo[(((ib * 2 + il) * 20 + rem) * 64 + lane2) * 8] =
            *(const half8*)&scratch[row * 328 + col];
    }
}

// ---------------- fused va + softmax + pooling: 2 items/block ------------
__global__ __launch_bounds__(512, 4) void vapool_kernel(
    const f16* __restrict__ xF, const f16* __restrict__ wvaF,
    const float* __restrict__ bva, const float* __restrict__ qw,
    f16* __restrict__ cbar) {
    __shared__ float aL[64];
    __shared__ float alpha[64];
    __shared__ float cacc[640];
    const int ib = blockIdx.x, tid = threadIdx.x;
    const int w = tid >> 6, lane = tid & 63, lr = lane & 15, quad = lane >> 4;
    const int mh = w >> 2, nsub = w & 3;
    const float4v vz = {0.f, 0.f, 0.f, 0.f};
    for (int i = tid; i < 64; i += 512) aL[i] = 0.f;
    for (int i = tid; i < 640; i += 512) cacc[i] = 0.f;
    __syncthreads();
    // GEMM: rows = items ib*2 (mt=mh) and ib*2+1 (mt=mh+2); 5 ntiles per wave
    float4v acc[2][5];
#pragma unroll
    for (int z = 0; z < 2; ++z)
#pragma unroll
        for (int i = 0; i < 5; ++i) acc[z][i] = vz;
    for (int ks = 0; ks < 10; ++ks) {
        half8 a0 = *(const half8*)&xF[(((ib * 4 + mh) * 10 + ks) * 64 + lane) * 8];
        half8 a1 = *(const half8*)&xF[(((ib * 4 + mh + 2) * 10 + ks) * 64 + lane) * 8];
#pragma unroll
        for (int i = 0; i < 5; ++i) {
            half8 bf = *(const half8*)&wvaF[((((nsub * 5 + i) * 10) + ks) * 64 + lane) * 8];
            acc[0][i] = MFMA16(a0, bf, acc[0][i]);
            acc[1][i] = MFMA16(a1, bf, acc[1][i]);
        }
    }
#pragma unroll
    for (int i = 0; i < 5; ++i) {
        int n = (nsub * 5 + i) * 16 + lr;
        float bb = bva[n];
        float qq = (n < 300) ? qw[n] : 0.f;
#pragma unroll
        for (int z = 0; z < 2; ++z)
#pragma unroll
            for (int r = 0; r < 4; ++r) {
                float p = tanhf(acc[z][i][r] + bb) * qq;
#pragma unroll
                for (int off = 1; off < 16; off <<= 1) p += __shfl_xor(p, off, 64);
                if (lr == 0) atomicAdd(&aL[z * 32 + mh * 16 + quad * 4 + r], p);
            }
    }
    __syncthreads();
    if (w == 0) {  // two 32-row softmaxes (lanes 0-31: item0, 32-63: item1)
        float av = aL[lane];
        float m = av;
#pragma unroll
        for (int off = 1; off < 32; off <<= 1) m = fmaxf(m, __shfl_xor(m, off, 64));
        float e = expf(av - m);
        float ss = e;
#pragma unroll
        for (int off = 1; off < 32; off <<= 1) ss += __shfl_xor(ss, off, 64);
        alpha[lane] = e / ss;
    }
    __syncthreads();
    // pooled sum: 40 frag chunks (2 items x 20), wave w takes chunks w+8i
#pragma unroll
    for (int i = 0; i < 5; ++i) {
        int ch = w + 8 * i;
        int it = ch / 20, rem = ch - it * 20;
        int mtl = rem / 10, ks = rem - mtl * 10;
        half8 v = *(const half8*)&xF[(((ib * 2 + it) * 20 + rem) * 64 + lane) * 8];
        float sc = alpha[it * 32 + mtl * 16 + lr];
        float p[8];
#pragma unroll
        for (int j = 0; j < 8; ++j) p[j] = (float)v[j] * sc;
#pragma unroll
        for (int off = 1; off < 16; off <<= 1)
#pragma unroll
            for (int j = 0; j < 8; ++j) p[j] += __shfl_xor(p[j], off, 64);
        if (lr == 0) {
#pragma unroll
            for (int j = 0; j < 8; ++j)
                atomicAdd(&cacc[it * 320 + ks * 32 + quad * 8 + j], p[j]);
        }
    }
    __syncthreads();
    for (int i = tid; i < 640; i += 512) cbar[ib * 640 + i] = (f16)cacc[i];
}

// ---------------- out = cbar @ Wo^T + bo, f32 [4096][300] ----------------
__global__ __launch_bounds__(512) void out_kernel(
    const f16* __restrict__ cbar, const f16* __restrict__ wo16F,
    const float* __restrict__ bo, float* __restrict__ out) {
    __shared__ __align__(16) f16 cA[32 * 328];
    const int mb = blockIdx.x, tid = threadIdx.x;  // 128 blocks, M=32
    const int w = tid >> 6, lane = tid & 63, lr = lane & 15, quad = lane >> 4;
    const int mh = w >> 2, nsub = w & 3;
    for (int i = tid; i < 1280; i += 512) {
        int row = i / 40, g = i - row * 40;
        *(half8*)&cA[row * 328 + g * 8] = *(const half8*)&cbar[(mb * 32 + row) * 320 + g * 8];
    }
    __syncthreads();
    const float4v vz = {0.f, 0.f, 0.f, 0.f};
    float4v acc[5];
#pragma unroll
    for (int i = 0; i < 5; ++i) acc[i] = vz;
    for (int ks = 0; ks < 10; ++ks) {
        half8 a = *(const half8*)&cA[(mh * 16 + lr) * 328 + ks * 32 + quad * 8];
#pragma unroll
        for (int i = 0; i < 5; ++i) {
            half8 bf = *(const half8*)&wo16F[((((nsub * 5 + i) * 10) + ks) * 64 + lane) * 8];
            acc[i] = MFMA16(a, bf, acc[i]);
        }
    }
#pragma unroll
    for (int i = 0; i < 5; ++i) {
        int n = (nsub * 5 + i) * 16 + lr;
        if (n < 300) {
            float bb = bo[n];
#pragma unroll
            for (int r = 0; r < 4; ++r)
                out[(mb * 32 + mh * 16 + quad * 4 + r) * 300 + n] = acc[i][r] + bb;
        }
    }
}

// ---------------- host launcher ----------------
extern "C" void kernel_launch(void* const* d_in, const int* in_sizes, int n_in,
                              void* d_out, int out_size, void* d_ws, size_t ws_size,
                              hipStream_t stream) {
    const int* title = (const int*)d_in[0];
    const float* emb = (const float*)d_in[1];
    const float* pos = (const float*)d_in[2];
    const float* Wq = (const float*)d_in[3];
    const float* bq = (const float*)d_in[4];
    const float* Wk = (const float*)d_in[5];
    const float* bk = (const float*)d_in[6];
    const float* Wv = (const float*)d_in[7];
    const float* bv = (const float*)d_in[8];
    const float* Wo = (const float*)d_in[9];
    const float* bo = (const float*)d_in[10];
    const float* Va = (const float*)d_in[11];
    const float* ba = (const float*)d_in[12];
    const float* qw = (const float*)d_in[13];
    char* ws = (char*)d_ws;
    float* out = (float*)d_out;

    f16* wqkvF = (f16*)(ws + WQKV_OFF);
    float* bqkv = (float*)(ws + BQKV_OFF);
    f16* wo16F = (f16*)(ws + WO_OFF);
    f16* wvaF = (f16*)(ws + WVA_OFF);
    float* bva = (float*)(ws + BVA_OFF);
    f16* cbar = (f16*)(ws + CBAR_OFF);
    f16* xF = (f16*)(ws + XF_OFF);

    repack1<<<1684, 256, 0, stream>>>(Wq, Wk, Wv, Wo, bq, bk, bv, wqkvF, wo16F, bqkv);
    repack2<<<400, 64, 0, stream>>>(Va, Wo, wvaF);
    repack3<<<1, 320, 0, stream>>>(Va, bo, ba, bva);
    gather_kernel<<<20480, 256, 0, stream>>>(title, emb, pos, xF);
    qkvattn_kernel<<<2048, 1024, 0, stream>>>(xF, wqkvF, bqkv, xF);
    vapool_kernel<<<2048, 512, 0, stream>>>(xF, wvaF, bva, qw, cbar);
    out_kernel<<<128, 512, 0, stream>>>(cbar, wo16F, bo, out);
}

// Round 6
// 435.298 us; speedup vs baseline: 1.9631x; 1.1518x over previous
//
#include <hip/hip_runtime.h>
#include <math.h>

typedef _Float16 f16;
typedef _Float16 half8 __attribute__((ext_vector_type(8)));
typedef _Float16 half4 __attribute__((ext_vector_type(4)));
typedef float float4v __attribute__((ext_vector_type(4)));

#define MFMA16(a, b, c) __builtin_amdgcn_mfma_f32_16x16x32_f16((a), (b), (c), 0, 0, 0)

// problem: B=4096 L=32 V=50000 D=300 H=6 HD=50 ; K padded to 320
// Fragment-swizzled layout: element (n, k) of a [Nt*16][320] matrix lives at
//   F[((n>>4)*10 + (k>>5))*512 + (((k>>3)&3)*16 + (n&15))*8 + (k&7)]

// ---------------- ws layout (bytes) ----------------
#define WQKV_OFF 0u          // f16 frag-swizzled [64 ntiles] (q*rs | k | v rows, pads 0)
#define BQKV_OFF 655360u     // f32 [1024]
#define WO_OFF   659456u     // f16 frag-swizzled [20 ntiles] Wo
#define WVA_OFF  864256u     // f16 frag-swizzled [20 ntiles] Va@Wo
#define BVA_OFF  1069056u    // f32 [320]  Va@bo+ba (pads 0)
#define CBAR_OFF 1070336u    // f16 [4096][320] row-major
#define XF_OFF   3691776u    // f16 frag-swizzled x: per item 20 fragblks of 512

// ---------------- repack1: Wqkv + Wo -> frag-swizzled f16, bqkv ----------
__global__ void repack1(const float* __restrict__ Wq, const float* __restrict__ Wk,
                        const float* __restrict__ Wv, const float* __restrict__ Wo,
                        const float* __restrict__ bq, const float* __restrict__ bk,
                        const float* __restrict__ bv,
                        f16* __restrict__ wqkvF, f16* __restrict__ wo16F,
                        float* __restrict__ bqkv) {
    int idx = blockIdx.x * 256 + threadIdx.x;
    const float rs = 0.14142135623730951f;  // 1/sqrt(50)
    if (idx < 327680) {  // wqkvF: 64 ntiles
        int ntile = idx / 5120, rem = idx - ntile * 5120;
        int ks = rem / 512, r2 = rem - ks * 512;
        int lane = r2 >> 3, j = r2 & 7;
        int n = ntile * 16 + (lane & 15);
        int k = ks * 32 + (lane >> 4) * 8 + j;
        int g = n / 320, r = n - g * 320;
        float v = 0.f;
        if (r < 300 && k < 300) {
            if (g == 0) v = Wq[r * 300 + k] * rs;
            else if (g == 1) v = Wk[r * 300 + k];
            else if (g == 2) v = Wv[r * 300 + k];
        }
        wqkvF[idx] = (f16)v;
    } else if (idx < 430080) {  // wo16F: 20 ntiles
        int t = idx - 327680;
        int ntile = t / 5120, rem = t - ntile * 5120;
        int ks = rem / 512, r2 = rem - ks * 512;
        int lane = r2 >> 3, j = r2 & 7;
        int n = ntile * 16 + (lane & 15);
        int k = ks * 32 + (lane >> 4) * 8 + j;
        wo16F[t] = (f16)((n < 300 && k < 300) ? Wo[n * 300 + k] : 0.f);
    } else if (idx < 431104) {  // bqkv [1024]
        int n = idx - 430080;
        int g = n / 320, r = n - g * 320;
        float v = 0.f;
        if (r < 300) {
            if (g == 0) v = bq[r] * rs;
            else if (g == 1) v = bk[r];
            else if (g == 2) v = bv[r];
        }
        bqkv[n] = v;
    }
}

// ---------------- repack2: Wva = Va @ Wo -> frag-swizzled ----------------
__global__ void repack2(const float* __restrict__ Va, const float* __restrict__ Wo,
                        f16* __restrict__ wvaF) {
    int bt = blockIdx.x;  // 400 = 20*20
    int mt = bt / 20, nt = bt % 20;
    int lane = threadIdx.x & 63;
    int lr = lane & 15, quad = lane >> 4;
    float4v acc = {0.f, 0.f, 0.f, 0.f};
    int m = mt * 16 + lr;   // Wva row
    int nn = nt * 16 + lr;  // Wva col (= Wo output dim)
    for (int ks = 0; ks < 10; ++ks) {
        int c = ks * 32 + quad * 8;
        half8 af, bf;
#pragma unroll
        for (int j = 0; j < 8; ++j) {
            int cc = c + j;
            af[j] = (f16)((m < 300 && cc < 300) ? Va[m * 300 + cc] : 0.f);
            bf[j] = (f16)((nn < 300 && cc < 300) ? Wo[cc * 300 + nn] : 0.f);
        }
        acc = MFMA16(af, bf, acc);
    }
#pragma unroll
    for (int r = 0; r < 4; ++r) {
        int row = mt * 16 + quad * 4 + r;  // Wva row index (n of va GEMM)
        int col = nt * 16 + lr;            // Wva col index (k of va GEMM)
        int addr = ((row >> 4) * 10 + (col >> 5)) * 512 +
                   (((col >> 3) & 3) * 16 + (row & 15)) * 8 + (col & 7);
        wvaF[addr] = (f16)acc[r];
    }
}

// ---------------- repack3: bva = Va @ bo + ba ----------------
__global__ void repack3(const float* __restrict__ Va, const float* __restrict__ bo,
                        const float* __restrict__ ba, float* __restrict__ bva) {
    int j = threadIdx.x;  // 320
    float s = 0.f;
    if (j < 300) {
        for (int k = 0; k < 300; ++k) s += Va[j * 300 + k] * bo[k];
        s += ba[j];
    }
    bva[j] = s;
}

// ---------------- gather: x = emb[title] + pos, frag-swizzled ------------
__global__ void gather_kernel(const int* __restrict__ title, const float* __restrict__ emb,
                              const float* __restrict__ pos, f16* __restrict__ xF) {
    int c = blockIdx.x * 256 + threadIdx.x;  // < 131072*40
    int fragblk = c >> 6, lane = c & 63;
    int item = fragblk / 20, rem = fragblk - item * 20;
    int mt = rem / 10, ks = rem - mt * 10;
    int lr = lane & 15, quad = lane >> 4;
    int row = item * 32 + mt * 16 + lr;
    int col = ks * 32 + quad * 8;
    int t = title[row];
    int l = row & 31;
    half8 h;
    if (col + 8 <= 300) {
        float4v e0 = *(const float4v*)&emb[t * 300 + col];
        float4v e1 = *(const float4v*)&emb[t * 300 + col + 4];
        float4v p0 = *(const float4v*)&pos[l * 300 + col];
        float4v p1 = *(const float4v*)&pos[l * 300 + col + 4];
#pragma unroll
        for (int j = 0; j < 4; ++j) { h[j] = (f16)(e0[j] + p0[j]); h[4 + j] = (f16)(e1[j] + p1[j]); }
    } else {
#pragma unroll
        for (int j = 0; j < 8; ++j) {
            int cc = col + j;
            h[j] = (f16)((cc < 300) ? emb[t * 300 + cc] + pos[l * 300 + cc] : 0.f);
        }
    }
    *(half8*)&xF[c * 8] = h;
}

// ---- fused QKV GEMM + attention + va + softmax + pool: 2 items/block ----
// LDS: qL/kL [12*32][72], vT [12*64][32] = 159,744 B -> 1 block/CU, 16 waves
__global__ __launch_bounds__(1024, 4) void qkvattn_kernel(
    const f16* __restrict__ xF, const f16* __restrict__ wqkvF,
    const float* __restrict__ bqkv, const f16* __restrict__ wvaF,
    const float* __restrict__ bva, const float* __restrict__ qw,
    f16* __restrict__ cbar) {
    __shared__ __align__(16) f16 qL[12 * 32 * 72];
    __shared__ __align__(16) f16 kL[12 * 32 * 72];
    __shared__ __align__(16) f16 vT[12 * 64 * 32];
    __shared__ float aL[64];
    __shared__ float alpha[64];
    const int ib = blockIdx.x, tid = threadIdx.x;
    const int w = tid >> 6, lane = tid & 63, lr = lane & 15, quad = lane >> 4;
    const float4v vz = {0.f, 0.f, 0.f, 0.f};

    // zero q/k/v staging (pads must be 0) and aL
    for (int i = tid; i < 13824; i += 1024) { ((int*)qL)[i] = 0; ((int*)kL)[i] = 0; }
    for (int i = tid; i < 12288; i += 1024) ((int*)vT)[i] = 0;
    if (tid < 64) aL[tid] = 0.f;
    __syncthreads();

    // --- Phase 1: QKV GEMM, M=64 (items ib*2, ib*2+1), N=1024, K=320 ---
    {
        float4v acc[4][4];
#pragma unroll
        for (int mt = 0; mt < 4; ++mt)
#pragma unroll
            for (int j = 0; j < 4; ++j) acc[mt][j] = vz;
        for (int ks = 0; ks < 10; ++ks) {
            half8 a[4];
#pragma unroll
            for (int mt = 0; mt < 4; ++mt)
                a[mt] = *(const half8*)&xF[(((ib * 4 + mt) * 10 + ks) * 64 + lane) * 8];
#pragma unroll
            for (int j = 0; j < 4; ++j) {
                half8 bf = *(const half8*)&wqkvF[((((w * 4 + j) * 10) + ks) * 64 + lane) * 8];
#pragma unroll
                for (int mt = 0; mt < 4; ++mt) acc[mt][j] = MFMA16(a[mt], bf, acc[mt][j]);
            }
        }
        // epilogue: scatter q/k/v into LDS (wi is wave-uniform per j: 4 | 20)
#pragma unroll
        for (int j = 0; j < 4; ++j) {
            int tile = w * 4 + j;
            int wi = tile / 20;
            int n = tile * 16 + lr;
            int cc = n - wi * 320;
            float bb = (wi < 3) ? bqkv[n] : 0.f;
            int h = cc / 50, d = cc - h * 50;
            if (wi < 3 && cc < 300) {
                if (wi == 2) {  // v: 4 contiguous rows -> packed b64 write
#pragma unroll
                    for (int mt = 0; mt < 4; ++mt) {
                        int hh = (mt >> 1) * 6 + h;
                        int row0 = (mt & 1) * 16 + quad * 4;
                        half4 pk;
#pragma unroll
                        for (int r = 0; r < 4; ++r) pk[r] = (f16)(acc[mt][j][r] + bb);
                        *(half4*)&vT[(hh * 64 + d) * 32 + row0] = pk;
                    }
                } else {
                    f16* dst = (wi == 0) ? qL : kL;
#pragma unroll
                    for (int mt = 0; mt < 4; ++mt) {
                        int hh = (mt >> 1) * 6 + h;
#pragma unroll
                        for (int r = 0; r < 4; ++r) {
                            int row = (mt & 1) * 16 + quad * 4 + r;
                            dst[(hh * 32 + row) * 72 + d] = (f16)(acc[mt][j][r] + bb);
                        }
                    }
                }
            }
        }
    }
    __syncthreads();

    // --- Phase 2: wave hh (<12) computes scores + softmax -> P (aliases qL) ---
    const int hh = w;
    if (w < 12) {
        float4v s00 = vz, s01 = vz, s10 = vz, s11 = vz;
#pragma unroll
        for (int ks = 0; ks < 2; ++ks) {
            int c = ks * 32 + quad * 8;
            half8 aq0 = *(const half8*)&qL[(hh * 32 + lr) * 72 + c];
            half8 aq1 = *(const half8*)&qL[(hh * 32 + 16 + lr) * 72 + c];
            half8 bk0 = *(const half8*)&kL[(hh * 32 + lr) * 72 + c];
            half8 bk1 = *(const half8*)&kL[(hh * 32 + 16 + lr) * 72 + c];
            s00 = MFMA16(aq0, bk0, s00);
            s01 = MFMA16(aq0, bk1, s01);
            s10 = MFMA16(aq1, bk0, s10);
            s11 = MFMA16(aq1, bk1, s11);
        }
        f16* ph = qL + hh * 32 * 72;
#pragma unroll
        for (int mt = 0; mt < 2; ++mt) {
            float4v sv0 = mt ? s10 : s00;
            float4v sv1 = mt ? s11 : s01;
#pragma unroll
            for (int r = 0; r < 4; ++r) {
                float v0 = sv0[r], v1 = sv1[r];
                float m = fmaxf(v0, v1);
#pragma unroll
                for (int off = 1; off < 16; off <<= 1) m = fmaxf(m, __shfl_xor(m, off, 64));
                float e0 = expf(v0 - m), e1 = expf(v1 - m);
                float ss = e0 + e1;
#pragma unroll
                for (int off = 1; off < 16; off <<= 1) ss += __shfl_xor(ss, off, 64);
                float inv = 1.0f / ss;
                int row = mt * 16 + quad * 4 + r;
                ph[row * 40 + lr] = (f16)(e0 * inv);
                ph[row * 40 + 16 + lr] = (f16)(e1 * inv);
            }
        }
    }
    __syncthreads();

    // --- Phase 3: ctx = P @ V -> row-major scratch (reuses kL, [64][328]) ---
    f16* scratch = kL;
    for (int i = tid; i < 64 * 28; i += 1024) {  // zero pad cols 300..327
        int row = i / 28, cc = 300 + (i - row * 28);
        scratch[row * 328 + cc] = (f16)0.f;
    }
    if (w < 12) {
        int il = hh / 6, h = hh - il * 6;
        f16* ph = qL + hh * 32 * 72;
        half8 aw0 = *(const half8*)&ph[lr * 40 + quad * 8];
        half8 aw1 = *(const half8*)&ph[(16 + lr) * 40 + quad * 8];
        float4v c0[4], c1[4];
#pragma unroll
        for (int nt = 0; nt < 4; ++nt) { c0[nt] = vz; c1[nt] = vz; }
#pragma unroll
        for (int nt = 0; nt < 4; ++nt) {
            half8 bvf = *(const half8*)&vT[(hh * 64 + nt * 16 + lr) * 32 + quad * 8];
            c0[nt] = MFMA16(aw0, bvf, c0[nt]);
            c1[nt] = MFMA16(aw1, bvf, c1[nt]);
        }
#pragma unroll
        for (int mt = 0; mt < 2; ++mt)
#pragma unroll
            for (int nt = 0; nt < 4; ++nt)
#pragma unroll
                for (int r = 0; r < 4; ++r) {
                    int d = nt * 16 + lr;
                    if (d < 50) {
                        int row = il * 32 + mt * 16 + quad * 4 + r;
                        float4v cv = mt ? c1[nt] : c0[nt];
                        scratch[row * 328 + h * 50 + d] = (f16)cv[r];
                    }
                }
    }
    __syncthreads();

    // --- Phase 4: va GEMM from scratch: y = ctx @ Wva^T + bva; a[l] = sum tanh(y)*qw ---
    {
        const int mtile = w >> 2, nsub = w & 3;  // 4 m-tiles x 4 n-groups, 5 ntiles each
        float4v vacc[5];
#pragma unroll
        for (int i = 0; i < 5; ++i) vacc[i] = vz;
        const int arow = (mtile * 16 + lr) * 328;
        for (int ks = 0; ks < 10; ++ks) {
            half8 a = *(const half8*)&scratch[arow + ks * 32 + quad * 8];
#pragma unroll
            for (int i = 0; i < 5; ++i) {
                half8 bf = *(const half8*)&wvaF[((((nsub * 5 + i) * 10) + ks) * 64 + lane) * 8];
                vacc[i] = MFMA16(a, bf, vacc[i]);
            }
        }
        float ps[4] = {0.f, 0.f, 0.f, 0.f};
#pragma unroll
        for (int i = 0; i < 5; ++i) {
            int n = (nsub * 5 + i) * 16 + lr;
            float bb = bva[n];
            float qq = (n < 300) ? qw[n] : 0.f;
#pragma unroll
            for (int r = 0; r < 4; ++r) ps[r] += tanhf(vacc[i][r] + bb) * qq;
        }
#pragma unroll
        for (int r = 0; r < 4; ++r)
#pragma unroll
            for (int off = 1; off < 16; off <<= 1) ps[r] += __shfl_xor(ps[r], off, 64);
        if (lr == 0) {
#pragma unroll
            for (int r = 0; r < 4; ++r) atomicAdd(&aL[mtile * 16 + quad * 4 + r], ps[r]);
        }
    }
    __syncthreads();

    // --- Phase 5: two 32-row softmaxes (lanes 0-31 item0, 32-63 item1) ---
    if (w == 0) {
        float av = aL[lane];
        float m = av;
#pragma unroll
        for (int off = 1; off < 32; off <<= 1) m = fmaxf(m, __shfl_xor(m, off, 32));
        float e = expf(av - m);
        float ss = e;
#pragma unroll
        for (int off = 1; off < 32; off <<= 1) ss += __shfl_xor(ss, off, 32);
        alpha[lane] = e / ss;
    }
    __syncthreads();

    // --- Phase 6: cbar[it][d] = sum_l alpha[it*32+l] * ctx[it*32+l][d] ---
    if (tid < 640) {
        int it = tid / 320, d = tid - it * 320;
        float acc = 0.f;
#pragma unroll
        for (int l = 0; l < 32; ++l)
            acc += alpha[it * 32 + l] * (float)scratch[(it * 32 + l) * 328 + d];
        cbar[ib * 640 + tid] = (f16)acc;
    }
}

// ---------------- out = cbar @ Wo^T + bo, f32 [4096][300] ----------------
__global__ __launch_bounds__(512) void out_kernel(
    const f16* __restrict__ cbar, const f16* __restrict__ wo16F,
    const float* __restrict__ bo, float* __restrict__ out) {
    __shared__ __align__(16) f16 cA[32 * 328];
    const int mb = blockIdx.x, tid = threadIdx.x;  // 128 blocks, M=32
    const int w = tid >> 6, lane = tid & 63, lr = lane & 15, quad = lane >> 4;
    const int mh = w >> 2, nsub = w & 3;
    for (int i = tid; i < 1280; i += 512) {
        int row = i / 40, g = i - row * 40;
        *(half8*)&cA[row * 328 + g * 8] = *(const half8*)&cbar[(mb * 32 + row) * 320 + g * 8];
    }
    __syncthreads();
    const float4v vz = {0.f, 0.f, 0.f, 0.f};
    float4v acc[5];
#pragma unroll
    for (int i = 0; i < 5; ++i) acc[i] = vz;
    for (int ks = 0; ks < 10; ++ks) {
        half8 a = *(const half8*)&cA[(mh * 16 + lr) * 328 + ks * 32 + quad * 8];
#pragma unroll
        for (int i = 0; i < 5; ++i) {
            half8 bf = *(const half8*)&wo16F[((((nsub * 5 + i) * 10) + ks) * 64 + lane) * 8];
            acc[i] = MFMA16(a, bf, acc[i]);
        }
    }
#pragma unroll
    for (int i = 0; i < 5; ++i) {
        int n = (nsub * 5 + i) * 16 + lr;
        if (n < 300) {
            float bb = bo[n];
#pragma unroll
            for (int r = 0; r < 4; ++r)
                out[(mb * 32 + mh * 16 + quad * 4 + r) * 300 + n] = acc[i][r] + bb;
        }
    }
}

// ---------------- host launcher ----------------
extern "C" void kernel_launch(void* const* d_in, const int* in_sizes, int n_in,
                              void* d_out, int out_size, void* d_ws, size_t ws_size,
                              hipStream_t stream) {
    const int* title = (const int*)d_in[0];
    const float* emb = (const float*)d_in[1];
    const float* pos = (const float*)d_in[2];
    const float* Wq = (const float*)d_in[3];
    const float* bq = (const float*)d_in[4];
    const float* Wk = (const float*)d_in[5];
    const float* bk = (const float*)d_in[6];
    const float* Wv = (const float*)d_in[7];
    const float* bv = (const float*)d_in[8];
    const float* Wo = (const float*)d_in[9];
    const float* bo = (const float*)d_in[10];
    const float* Va = (const float*)d_in[11];
    const float* ba = (const float*)d_in[12];
    const float* qw = (const float*)d_in[13];
    char* ws = (char*)d_ws;
    float* out = (float*)d_out;

    f16* wqkvF = (f16*)(ws + WQKV_OFF);
    float* bqkv = (float*)(ws + BQKV_OFF);
    f16* wo16F = (f16*)(ws + WO_OFF);
    f16* wvaF = (f16*)(ws + WVA_OFF);
    float* bva = (float*)(ws + BVA_OFF);
    f16* cbar = (f16*)(ws + CBAR_OFF);
    f16* xF = (f16*)(ws + XF_OFF);

    repack1<<<1684, 256, 0, stream>>>(Wq, Wk, Wv, Wo, bq, bk, bv, wqkvF, wo16F, bqkv);
    repack2<<<400, 64, 0, stream>>>(Va, Wo, wvaF);
    repack3<<<1, 320, 0, stream>>>(Va, bo, ba, bva);
    gather_kernel<<<20480, 256, 0, stream>>>(title, emb, pos, xF);
    qkvattn_kernel<<<2048, 1024, 0, stream>>>(xF, wqkvF, bqkv, wvaF, bva, qw, cbar);
    out_kernel<<<128, 512, 0, stream>>>(cbar, wo16F, bo, out);
}